// Round 1
// baseline (1536.113 us; speedup 1.0000x reference)
//
#include <hip/hip_runtime.h>

#define N_NODES 100000
#define IN_F 256
#define OUT_F 128
#define TILE_M 64
#define TILE_K 64

// -------- Kernel 1: support = X (100000x256) @ W (256x128), fp32 --------
// Block = 256 threads, computes a 64-row x 128-col tile.
// Thread (colg = t&31, rowg = t>>5) owns an 8-row x 4-col register tile.
// LDS: Xs[64][68] (pad 4 keeps float4/float2 alignment, 2-way-max conflicts),
//      Ws[64][128].
__global__ __launch_bounds__(256) void gemm_xw(const float* __restrict__ x,
                                               const float* __restrict__ w,
                                               float* __restrict__ support) {
  __shared__ float Xs[TILE_M][TILE_K + 4];
  __shared__ float Ws[TILE_K][OUT_F];
  const int t = threadIdx.x;
  const int row0 = blockIdx.x * TILE_M;
  const int colg = t & 31;   // cols colg*4 .. colg*4+3
  const int rowg = t >> 5;   // rows rowg*8 .. rowg*8+7

  float acc[8][4];
#pragma unroll
  for (int r = 0; r < 8; ++r)
#pragma unroll
    for (int c = 0; c < 4; ++c) acc[r][c] = 0.0f;

  const int lrow = t >> 4;       // 0..15 (X loader row)
  const int lk = (t & 15) * 4;   // 0..60 (X loader k, float4)
  const int wrow = t >> 5;       // 0..7  (W loader row)
  const int wn = (t & 31) * 4;   // 0..124 (W loader col, float4)

  for (int k0 = 0; k0 < IN_F; k0 += TILE_K) {
#pragma unroll
    for (int i = 0; i < 4; ++i) {
      int row = row0 + lrow + 16 * i;
      float4 v = make_float4(0.f, 0.f, 0.f, 0.f);
      if (row < N_NODES)
        v = *(const float4*)(x + (size_t)row * IN_F + k0 + lk);
      *(float4*)&Xs[lrow + 16 * i][lk] = v;
    }
#pragma unroll
    for (int i = 0; i < 8; ++i) {
      int kr = k0 + wrow + 8 * i;
      *(float4*)&Ws[wrow + 8 * i][wn] = *(const float4*)(w + (size_t)kr * OUT_F + wn);
    }
    __syncthreads();

#pragma unroll 8
    for (int kk = 0; kk < TILE_K; kk += 2) {
      float4 w0 = *(const float4*)&Ws[kk][colg * 4];
      float4 w1 = *(const float4*)&Ws[kk + 1][colg * 4];
#pragma unroll
      for (int r = 0; r < 8; ++r) {
        float2 xv = *(const float2*)&Xs[rowg * 8 + r][kk];
        acc[r][0] = fmaf(xv.x, w0.x, acc[r][0]);
        acc[r][1] = fmaf(xv.x, w0.y, acc[r][1]);
        acc[r][2] = fmaf(xv.x, w0.z, acc[r][2]);
        acc[r][3] = fmaf(xv.x, w0.w, acc[r][3]);
        acc[r][0] = fmaf(xv.y, w1.x, acc[r][0]);
        acc[r][1] = fmaf(xv.y, w1.y, acc[r][1]);
        acc[r][2] = fmaf(xv.y, w1.z, acc[r][2]);
        acc[r][3] = fmaf(xv.y, w1.w, acc[r][3]);
      }
    }
    __syncthreads();
  }

#pragma unroll
  for (int r = 0; r < 8; ++r) {
    int row = row0 + rowg * 8 + r;
    if (row < N_NODES) {
      float4 o = make_float4(acc[r][0], acc[r][1], acc[r][2], acc[r][3]);
      *(float4*)(support + (size_t)row * OUT_F + colg * 4) = o;
    }
  }
}

// -------- Kernel 2: out[dst] += w_e * support[src], one wave per edge -----
// lane handles 2 consecutive floats (float2 gather is a coalesced 512B/wave
// read); 2 fp32 global atomics per lane.
__global__ __launch_bounds__(256) void scatter_edges(const int* __restrict__ ei,
                                                     const float* __restrict__ ew,
                                                     const float* __restrict__ support,
                                                     float* __restrict__ out,
                                                     int nedges) {
  int gwave = (int)((blockIdx.x * 256u + threadIdx.x) >> 6);
  int lane = threadIdx.x & 63;
  if (gwave >= nedges) return;
  int dst = ei[gwave];            // row 0 of edge_index
  int src = ei[nedges + gwave];   // row 1 of edge_index
  float wgt = ew[gwave];
  float2 v = *(const float2*)(support + (size_t)src * OUT_F + lane * 2);
  float* op = out + (size_t)dst * OUT_F + lane * 2;
  atomicAdd(op, v.x * wgt);
  atomicAdd(op + 1, v.y * wgt);
}

extern "C" void kernel_launch(void* const* d_in, const int* in_sizes, int n_in,
                              void* d_out, int out_size, void* d_ws, size_t ws_size,
                              hipStream_t stream) {
  const float* x = (const float*)d_in[0];
  const int* ei = (const int*)d_in[1];        // [2, E] int32, flat
  const float* ew = (const float*)d_in[2];    // [E]
  const float* w = (const float*)d_in[3];     // [256,128]
  float* out = (float*)d_out;                 // [100000,128] fp32
  float* support = (float*)d_ws;              // [100000,128] fp32 scratch
  const int nedges = in_sizes[2];

  // d_out is poisoned 0xAA before every launch — zero it for the atomics.
  hipMemsetAsync(d_out, 0, (size_t)out_size * sizeof(float), stream);

  int gblocks = (N_NODES + TILE_M - 1) / TILE_M;
  gemm_xw<<<gblocks, 256, 0, stream>>>(x, w, support);

  int sblocks = (nedges + 3) / 4;  // 4 waves (edges) per block
  scatter_edges<<<sblocks, 256, 0, stream>>>(ei, ew, support, out, nedges);
}

// Round 2
// 538.356 us; speedup vs baseline: 2.8533x; 2.8533x over previous
//
#include <hip/hip_runtime.h>

#define N_NODES 100000
#define IN_F 256
#define OUT_F 128
#define TILE_M 64
#define TILE_K 64
#define SCAN_ELEMS 1024

// -------- Kernel 1: support = X (100000x256) @ W (256x128), fp32 --------
__global__ __launch_bounds__(256) void gemm_xw(const float* __restrict__ x,
                                               const float* __restrict__ w,
                                               float* __restrict__ support) {
  __shared__ float Xs[TILE_M][TILE_K + 4];
  __shared__ float Ws[TILE_K][OUT_F];
  const int t = threadIdx.x;
  const int row0 = blockIdx.x * TILE_M;
  const int colg = t & 31;
  const int rowg = t >> 5;

  float acc[8][4];
#pragma unroll
  for (int r = 0; r < 8; ++r)
#pragma unroll
    for (int c = 0; c < 4; ++c) acc[r][c] = 0.0f;

  const int lrow = t >> 4;
  const int lk = (t & 15) * 4;
  const int wrow = t >> 5;
  const int wn = (t & 31) * 4;

  for (int k0 = 0; k0 < IN_F; k0 += TILE_K) {
#pragma unroll
    for (int i = 0; i < 4; ++i) {
      int row = row0 + lrow + 16 * i;
      float4 v = make_float4(0.f, 0.f, 0.f, 0.f);
      if (row < N_NODES)
        v = *(const float4*)(x + (size_t)row * IN_F + k0 + lk);
      *(float4*)&Xs[lrow + 16 * i][lk] = v;
    }
#pragma unroll
    for (int i = 0; i < 8; ++i) {
      int kr = k0 + wrow + 8 * i;
      *(float4*)&Ws[wrow + 8 * i][wn] = *(const float4*)(w + (size_t)kr * OUT_F + wn);
    }
    __syncthreads();

#pragma unroll 8
    for (int kk = 0; kk < TILE_K; kk += 2) {
      float4 w0 = *(const float4*)&Ws[kk][colg * 4];
      float4 w1 = *(const float4*)&Ws[kk + 1][colg * 4];
#pragma unroll
      for (int r = 0; r < 8; ++r) {
        float2 xv = *(const float2*)&Xs[rowg * 8 + r][kk];
        acc[r][0] = fmaf(xv.x, w0.x, acc[r][0]);
        acc[r][1] = fmaf(xv.x, w0.y, acc[r][1]);
        acc[r][2] = fmaf(xv.x, w0.z, acc[r][2]);
        acc[r][3] = fmaf(xv.x, w0.w, acc[r][3]);
        acc[r][0] = fmaf(xv.y, w1.x, acc[r][0]);
        acc[r][1] = fmaf(xv.y, w1.y, acc[r][1]);
        acc[r][2] = fmaf(xv.y, w1.z, acc[r][2]);
        acc[r][3] = fmaf(xv.y, w1.w, acc[r][3]);
      }
    }
    __syncthreads();
  }

#pragma unroll
  for (int r = 0; r < 8; ++r) {
    int row = row0 + rowg * 8 + r;
    if (row < N_NODES) {
      float4 o = make_float4(acc[r][0], acc[r][1], acc[r][2], acc[r][3]);
      *(float4*)(support + (size_t)row * OUT_F + colg * 4) = o;
    }
  }
}

// -------- CSR build: histogram of dst into rowptr[d+1] --------
__global__ __launch_bounds__(256) void hist_dst(const int* __restrict__ ei,
                                                int* __restrict__ rowptr, int nedges) {
  int e = blockIdx.x * 256 + threadIdx.x;
  if (e < nedges) atomicAdd(&rowptr[ei[e] + 1], 1);
}

// -------- in-place inclusive scan, 1024 elems / block --------
__global__ __launch_bounds__(256) void scan1(int* __restrict__ a,
                                             int* __restrict__ bsum, int n) {
  __shared__ int s[256];
  const int t = threadIdx.x;
  const int base = blockIdx.x * SCAN_ELEMS + t * 4;
  int v0 = (base + 0 < n) ? a[base + 0] : 0;
  int v1 = (base + 1 < n) ? a[base + 1] : 0;
  int v2 = (base + 2 < n) ? a[base + 2] : 0;
  int v3 = (base + 3 < n) ? a[base + 3] : 0;
  v1 += v0; v2 += v1; v3 += v2;
  s[t] = v3;
  __syncthreads();
  for (int off = 1; off < 256; off <<= 1) {
    int x = (t >= off) ? s[t - off] : 0;
    __syncthreads();
    s[t] += x;
    __syncthreads();
  }
  int excl = (t == 0) ? 0 : s[t - 1];
  if (base + 0 < n) a[base + 0] = v0 + excl;
  if (base + 1 < n) a[base + 1] = v1 + excl;
  if (base + 2 < n) a[base + 2] = v2 + excl;
  if (base + 3 < n) a[base + 3] = v3 + excl;
  if (t == 255 && bsum) bsum[blockIdx.x] = s[255];
}

__global__ __launch_bounds__(256) void scan3(int* __restrict__ a,
                                             const int* __restrict__ bsum, int n) {
  int b = blockIdx.x;
  if (b == 0) return;
  int add = bsum[b - 1];
  int i = b * SCAN_ELEMS + threadIdx.x * 4;
  if (i + 0 < n) a[i + 0] += add;
  if (i + 1 < n) a[i + 1] += add;
  if (i + 2 < n) a[i + 2] += add;
  if (i + 3 < n) a[i + 3] += add;
}

// -------- scatter edges into CSR slots: edges[pos] = (src, w_bits) --------
__global__ __launch_bounds__(256) void build_csr(const int* __restrict__ ei,
                                                 const float* __restrict__ ew,
                                                 int* __restrict__ cursor,
                                                 int2* __restrict__ edges, int nedges) {
  int e = blockIdx.x * 256 + threadIdx.x;
  if (e >= nedges) return;
  int dst = ei[e];
  int src = ei[nedges + e];
  float wgt = ew[e];
  int pos = atomicAdd(&cursor[dst], 1);
  edges[pos] = make_int2(src, __float_as_int(wgt));
}

// -------- aggregate: one wave per dst, no atomics --------
__global__ __launch_bounds__(256) void aggregate(const int* __restrict__ rowptr,
                                                 const int2* __restrict__ edges,
                                                 const float* __restrict__ support,
                                                 float* __restrict__ out, int nnodes) {
  int wave = (int)((blockIdx.x * 256u + threadIdx.x) >> 6);
  int lane = threadIdx.x & 63;
  if (wave >= nnodes) return;
  int beg = rowptr[wave];
  int end = rowptr[wave + 1];
  float2 acc = make_float2(0.f, 0.f);
  int e = beg;
  for (; e + 4 <= end; e += 4) {
    int2 m0 = edges[e + 0];
    int2 m1 = edges[e + 1];
    int2 m2 = edges[e + 2];
    int2 m3 = edges[e + 3];
    float2 v0 = *(const float2*)(support + (size_t)m0.x * OUT_F + lane * 2);
    float2 v1 = *(const float2*)(support + (size_t)m1.x * OUT_F + lane * 2);
    float2 v2 = *(const float2*)(support + (size_t)m2.x * OUT_F + lane * 2);
    float2 v3 = *(const float2*)(support + (size_t)m3.x * OUT_F + lane * 2);
    float w0 = __int_as_float(m0.y), w1 = __int_as_float(m1.y);
    float w2 = __int_as_float(m2.y), w3 = __int_as_float(m3.y);
    acc.x = fmaf(v0.x, w0, acc.x); acc.y = fmaf(v0.y, w0, acc.y);
    acc.x = fmaf(v1.x, w1, acc.x); acc.y = fmaf(v1.y, w1, acc.y);
    acc.x = fmaf(v2.x, w2, acc.x); acc.y = fmaf(v2.y, w2, acc.y);
    acc.x = fmaf(v3.x, w3, acc.x); acc.y = fmaf(v3.y, w3, acc.y);
  }
  for (; e < end; ++e) {
    int2 m = edges[e];
    float2 v = *(const float2*)(support + (size_t)m.x * OUT_F + lane * 2);
    float w = __int_as_float(m.y);
    acc.x = fmaf(v.x, w, acc.x);
    acc.y = fmaf(v.y, w, acc.y);
  }
  *(float2*)(out + (size_t)wave * OUT_F + lane * 2) = acc;
}

// -------- fallback (round-1 path) if ws too small --------
__global__ __launch_bounds__(256) void scatter_edges(const int* __restrict__ ei,
                                                     const float* __restrict__ ew,
                                                     const float* __restrict__ support,
                                                     float* __restrict__ out, int nedges) {
  int gwave = (int)((blockIdx.x * 256u + threadIdx.x) >> 6);
  int lane = threadIdx.x & 63;
  if (gwave >= nedges) return;
  int dst = ei[gwave];
  int src = ei[nedges + gwave];
  float wgt = ew[gwave];
  float2 v = *(const float2*)(support + (size_t)src * OUT_F + lane * 2);
  float* op = out + (size_t)dst * OUT_F + lane * 2;
  atomicAdd(op, v.x * wgt);
  atomicAdd(op + 1, v.y * wgt);
}

extern "C" void kernel_launch(void* const* d_in, const int* in_sizes, int n_in,
                              void* d_out, int out_size, void* d_ws, size_t ws_size,
                              hipStream_t stream) {
  const float* x = (const float*)d_in[0];
  const int* ei = (const int*)d_in[1];      // [2, E] int32 flat: row0=dst, row1=src
  const float* ew = (const float*)d_in[2];  // [E]
  const float* w = (const float*)d_in[3];   // [256,128]
  float* out = (float*)d_out;
  const int nedges = in_sizes[2];

  // workspace layout (bytes)
  const size_t off_support = 0;
  const size_t sz_support = (size_t)N_NODES * OUT_F * 4;          // 51,200,000
  const size_t off_rowptr = off_support + sz_support;             // 8-aligned
  const size_t sz_rowptr = (size_t)(N_NODES + 1) * 4;             // 400,004
  const size_t off_cursor = off_rowptr + 400008;                  // 51,600,008
  const size_t off_bsum = off_cursor + 400000;                    // 52,000,008
  const size_t off_edges = off_bsum + 408;                        // 52,000,416 (8-aligned)
  const size_t total_ws = off_edges + (size_t)nedges * 8;

  float* support = (float*)((char*)d_ws + off_support);
  int* rowptr = (int*)((char*)d_ws + off_rowptr);
  int* cursor = (int*)((char*)d_ws + off_cursor);
  int* bsum = (int*)((char*)d_ws + off_bsum);
  int2* edges = (int2*)((char*)d_ws + off_edges);

  const int gblocks = (N_NODES + TILE_M - 1) / TILE_M;
  gemm_xw<<<gblocks, 256, 0, stream>>>(x, w, support);

  if (ws_size < total_ws) {
    // fallback: atomic scatter
    hipMemsetAsync(d_out, 0, (size_t)out_size * sizeof(float), stream);
    int sblocks = (nedges + 3) / 4;
    scatter_edges<<<sblocks, 256, 0, stream>>>(ei, ew, support, out, nedges);
    return;
  }

  const int n1 = N_NODES + 1;
  const int nb = (n1 + SCAN_ELEMS - 1) / SCAN_ELEMS;  // 98
  const int eblocks = (nedges + 255) / 256;

  hipMemsetAsync(rowptr, 0, sz_rowptr, stream);
  hist_dst<<<eblocks, 256, 0, stream>>>(ei, rowptr, nedges);
  scan1<<<nb, 256, 0, stream>>>(rowptr, bsum, n1);
  scan1<<<1, 256, 0, stream>>>(bsum, (int*)nullptr, nb);
  scan3<<<nb, 256, 0, stream>>>(rowptr, bsum, n1);
  hipMemcpyAsync(cursor, rowptr, (size_t)N_NODES * 4, hipMemcpyDeviceToDevice, stream);
  build_csr<<<eblocks, 256, 0, stream>>>(ei, ew, cursor, edges, nedges);

  const int ablocks = (N_NODES + 3) / 4;  // 4 dst-waves per block
  aggregate<<<ablocks, 256, 0, stream>>>(rowptr, edges, support, out, N_NODES);
}

// Round 4
// 518.385 us; speedup vs baseline: 2.9633x; 1.0385x over previous
//
#include <hip/hip_runtime.h>

#define N_NODES 100000
#define IN_F 256
#define OUT_F 128
#define TILE_M 64
#define TILE_K 64
#define SCAN_ELEMS 1024
#define EDGE_ILP 8

// -------- Kernel 1: support = X (100000x256) @ W (256x128), fp32 --------
// (round-2 known-good version, unchanged)
__global__ __launch_bounds__(256) void gemm_xw(const float* __restrict__ x,
                                               const float* __restrict__ w,
                                               float* __restrict__ support) {
  __shared__ float Xs[TILE_M][TILE_K + 4];
  __shared__ float Ws[TILE_K][OUT_F];
  const int t = threadIdx.x;
  const int row0 = blockIdx.x * TILE_M;
  const int colg = t & 31;
  const int rowg = t >> 5;

  float acc[8][4];
#pragma unroll
  for (int r = 0; r < 8; ++r)
#pragma unroll
    for (int c = 0; c < 4; ++c) acc[r][c] = 0.0f;

  const int lrow = t >> 4;
  const int lk = (t & 15) * 4;
  const int wrow = t >> 5;
  const int wn = (t & 31) * 4;

  for (int k0 = 0; k0 < IN_F; k0 += TILE_K) {
#pragma unroll
    for (int i = 0; i < 4; ++i) {
      int row = row0 + lrow + 16 * i;
      float4 v = make_float4(0.f, 0.f, 0.f, 0.f);
      if (row < N_NODES)
        v = *(const float4*)(x + (size_t)row * IN_F + k0 + lk);
      *(float4*)&Xs[lrow + 16 * i][lk] = v;
    }
#pragma unroll
    for (int i = 0; i < 8; ++i) {
      int kr = k0 + wrow + 8 * i;
      *(float4*)&Ws[wrow + 8 * i][wn] = *(const float4*)(w + (size_t)kr * OUT_F + wn);
    }
    __syncthreads();

#pragma unroll 8
    for (int kk = 0; kk < TILE_K; kk += 2) {
      float4 w0 = *(const float4*)&Ws[kk][colg * 4];
      float4 w1 = *(const float4*)&Ws[kk + 1][colg * 4];
#pragma unroll
      for (int r = 0; r < 8; ++r) {
        float2 xv = *(const float2*)&Xs[rowg * 8 + r][kk];
        acc[r][0] = fmaf(xv.x, w0.x, acc[r][0]);
        acc[r][1] = fmaf(xv.x, w0.y, acc[r][1]);
        acc[r][2] = fmaf(xv.x, w0.z, acc[r][2]);
        acc[r][3] = fmaf(xv.x, w0.w, acc[r][3]);
        acc[r][0] = fmaf(xv.y, w1.x, acc[r][0]);
        acc[r][1] = fmaf(xv.y, w1.y, acc[r][1]);
        acc[r][2] = fmaf(xv.y, w1.z, acc[r][2]);
        acc[r][3] = fmaf(xv.y, w1.w, acc[r][3]);
      }
    }
    __syncthreads();
  }

#pragma unroll
  for (int r = 0; r < 8; ++r) {
    int row = row0 + rowg * 8 + r;
    if (row < N_NODES) {
      float4 o = make_float4(acc[r][0], acc[r][1], acc[r][2], acc[r][3]);
      *(float4*)(support + (size_t)row * OUT_F + colg * 4) = o;
    }
  }
}

// -------- CSR build: histogram of dst, 8 edges/thread (atomic-latency ILP) ----
__global__ __launch_bounds__(256) void hist_dst(const int* __restrict__ ei,
                                                int* __restrict__ rowptr,
                                                int nedges, int nth) {
  int t = blockIdx.x * 256 + threadIdx.x;
  int d[EDGE_ILP], ok[EDGE_ILP];
#pragma unroll
  for (int j = 0; j < EDGE_ILP; ++j) {
    int e = t + j * nth;
    ok[j] = e < nedges;
    d[j] = ei[ok[j] ? e : 0];
  }
#pragma unroll
  for (int j = 0; j < EDGE_ILP; ++j)
    if (ok[j]) atomicAdd(&rowptr[d[j] + 1], 1);
}

// -------- in-place inclusive scan, 1024 elems / block --------
__global__ __launch_bounds__(256) void scan1(int* __restrict__ a,
                                             int* __restrict__ bsum, int n) {
  __shared__ int s[256];
  const int t = threadIdx.x;
  const int base = blockIdx.x * SCAN_ELEMS + t * 4;
  int v0 = (base + 0 < n) ? a[base + 0] : 0;
  int v1 = (base + 1 < n) ? a[base + 1] : 0;
  int v2 = (base + 2 < n) ? a[base + 2] : 0;
  int v3 = (base + 3 < n) ? a[base + 3] : 0;
  v1 += v0; v2 += v1; v3 += v2;
  s[t] = v3;
  __syncthreads();
  for (int off = 1; off < 256; off <<= 1) {
    int x = (t >= off) ? s[t - off] : 0;
    __syncthreads();
    s[t] += x;
    __syncthreads();
  }
  int excl = (t == 0) ? 0 : s[t - 1];
  if (base + 0 < n) a[base + 0] = v0 + excl;
  if (base + 1 < n) a[base + 1] = v1 + excl;
  if (base + 2 < n) a[base + 2] = v2 + excl;
  if (base + 3 < n) a[base + 3] = v3 + excl;
  if (t == 255 && bsum) bsum[blockIdx.x] = s[255];
}

__global__ __launch_bounds__(256) void scan3(int* __restrict__ a,
                                             const int* __restrict__ bsum, int n) {
  int b = blockIdx.x;
  if (b == 0) return;
  int add = bsum[b - 1];
  int i = b * SCAN_ELEMS + threadIdx.x * 4;
  if (i + 0 < n) a[i + 0] += add;
  if (i + 1 < n) a[i + 1] += add;
  if (i + 2 < n) a[i + 2] += add;
  if (i + 3 < n) a[i + 3] += add;
}

// -------- scatter edges into CSR slots, 8 edges/thread ILP --------
__global__ __launch_bounds__(256) void build_csr(const int* __restrict__ ei,
                                                 const float* __restrict__ ew,
                                                 int* __restrict__ cursor,
                                                 int2* __restrict__ edges,
                                                 int nedges, int nth) {
  int t = blockIdx.x * 256 + threadIdx.x;
  int d[EDGE_ILP], s[EDGE_ILP], ok[EDGE_ILP];
  float wvl[EDGE_ILP];
#pragma unroll
  for (int j = 0; j < EDGE_ILP; ++j) {
    int e = t + j * nth;
    ok[j] = e < nedges;
    int ee = ok[j] ? e : 0;
    d[j] = ei[ee];
    s[j] = ei[nedges + ee];
    wvl[j] = ew[ee];
  }
  int pos[EDGE_ILP];
#pragma unroll
  for (int j = 0; j < EDGE_ILP; ++j)
    pos[j] = ok[j] ? atomicAdd(&cursor[d[j]], 1) : 0;
#pragma unroll
  for (int j = 0; j < EDGE_ILP; ++j)
    if (ok[j]) edges[pos[j]] = make_int2(s[j], __float_as_int(wvl[j]));
}

// -------- aggregate: one wave per dst, no atomics --------
__global__ __launch_bounds__(256) void aggregate(const int* __restrict__ rowptr,
                                                 const int2* __restrict__ edges,
                                                 const float* __restrict__ support,
                                                 float* __restrict__ out, int nnodes) {
  int wave = (int)((blockIdx.x * 256u + threadIdx.x) >> 6);
  int lane = threadIdx.x & 63;
  if (wave >= nnodes) return;
  int beg = rowptr[wave];
  int end = rowptr[wave + 1];
  float2 acc = make_float2(0.f, 0.f);
  int e = beg;
  for (; e + 4 <= end; e += 4) {
    int2 m0 = edges[e + 0];
    int2 m1 = edges[e + 1];
    int2 m2 = edges[e + 2];
    int2 m3 = edges[e + 3];
    float2 v0 = *(const float2*)(support + (size_t)m0.x * OUT_F + lane * 2);
    float2 v1 = *(const float2*)(support + (size_t)m1.x * OUT_F + lane * 2);
    float2 v2 = *(const float2*)(support + (size_t)m2.x * OUT_F + lane * 2);
    float2 v3 = *(const float2*)(support + (size_t)m3.x * OUT_F + lane * 2);
    float w0 = __int_as_float(m0.y), w1 = __int_as_float(m1.y);
    float w2 = __int_as_float(m2.y), w3 = __int_as_float(m3.y);
    acc.x = fmaf(v0.x, w0, acc.x); acc.y = fmaf(v0.y, w0, acc.y);
    acc.x = fmaf(v1.x, w1, acc.x); acc.y = fmaf(v1.y, w1, acc.y);
    acc.x = fmaf(v2.x, w2, acc.x); acc.y = fmaf(v2.y, w2, acc.y);
    acc.x = fmaf(v3.x, w3, acc.x); acc.y = fmaf(v3.y, w3, acc.y);
  }
  for (; e < end; ++e) {
    int2 m = edges[e];
    float2 v = *(const float2*)(support + (size_t)m.x * OUT_F + lane * 2);
    float w = __int_as_float(m.y);
    acc.x = fmaf(v.x, w, acc.x);
    acc.y = fmaf(v.y, w, acc.y);
  }
  *(float2*)(out + (size_t)wave * OUT_F + lane * 2) = acc;
}

// -------- fallback: atomic scatter (only if ws too small) --------
__global__ __launch_bounds__(256) void scatter_edges(const int* __restrict__ ei,
                                                     const float* __restrict__ ew,
                                                     const float* __restrict__ support,
                                                     float* __restrict__ out, int nedges) {
  int gwave = (int)((blockIdx.x * 256u + threadIdx.x) >> 6);
  int lane = threadIdx.x & 63;
  if (gwave >= nedges) return;
  int dst = ei[gwave];
  int src = ei[nedges + gwave];
  float wgt = ew[gwave];
  float2 v = *(const float2*)(support + (size_t)src * OUT_F + lane * 2);
  float* op = out + (size_t)dst * OUT_F + lane * 2;
  atomicAdd(op, v.x * wgt);
  atomicAdd(op + 1, v.y * wgt);
}

extern "C" void kernel_launch(void* const* d_in, const int* in_sizes, int n_in,
                              void* d_out, int out_size, void* d_ws, size_t ws_size,
                              hipStream_t stream) {
  const float* x = (const float*)d_in[0];
  const int* ei = (const int*)d_in[1];      // [2, E] int32 flat: row0=dst, row1=src
  const float* ew = (const float*)d_in[2];  // [E]
  const float* w = (const float*)d_in[3];   // [256,128]
  float* out = (float*)d_out;
  const int nedges = in_sizes[2];

  // workspace layout (bytes) — identical to round 2 (known good)
  const size_t off_support = 0;
  const size_t sz_support = (size_t)N_NODES * OUT_F * 4;  // 51,200,000
  const size_t off_rowptr = off_support + sz_support;
  const size_t sz_rowptr = (size_t)(N_NODES + 1) * 4;     // 400,004
  const size_t off_cursor = off_rowptr + 400008;          // 51,600,008
  const size_t off_bsum = off_cursor + 400000;            // 52,000,008
  const size_t off_edges = off_bsum + 408;                // 52,000,416 (8-aligned)
  const size_t total_ws = off_edges + (size_t)nedges * 8;

  float* support = (float*)((char*)d_ws + off_support);
  int* rowptr = (int*)((char*)d_ws + off_rowptr);
  int* cursor = (int*)((char*)d_ws + off_cursor);
  int* bsum = (int*)((char*)d_ws + off_bsum);
  int2* edges = (int2*)((char*)d_ws + off_edges);

  const int gblocks = (N_NODES + TILE_M - 1) / TILE_M;
  gemm_xw<<<gblocks, 256, 0, stream>>>(x, w, support);

  if (ws_size < total_ws) {
    hipMemsetAsync(d_out, 0, (size_t)out_size * sizeof(float), stream);
    int sblocks = (nedges + 3) / 4;
    scatter_edges<<<sblocks, 256, 0, stream>>>(ei, ew, support, out, nedges);
    return;
  }

  const int n1 = N_NODES + 1;
  const int nb = (n1 + SCAN_ELEMS - 1) / SCAN_ELEMS;          // 98
  const int eblocks = (nedges / EDGE_ILP + 255) / 256;        // 782
  const int nth = eblocks * 256;

  hipMemsetAsync(rowptr, 0, sz_rowptr, stream);
  hist_dst<<<eblocks, 256, 0, stream>>>(ei, rowptr, nedges, nth);
  scan1<<<nb, 256, 0, stream>>>(rowptr, bsum, n1);
  scan1<<<1, 256, 0, stream>>>(bsum, (int*)nullptr, nb);
  scan3<<<nb, 256, 0, stream>>>(rowptr, bsum, n1);
  hipMemcpyAsync(cursor, rowptr, (size_t)N_NODES * 4, hipMemcpyDeviceToDevice, stream);
  build_csr<<<eblocks, 256, 0, stream>>>(ei, ew, cursor, edges, nedges, nth);

  const int ablocks = (N_NODES + 3) / 4;
  aggregate<<<ablocks, 256, 0, stream>>>(rowptr, edges, support, out, N_NODES);
}

// Round 5
// 434.921 us; speedup vs baseline: 3.5319x; 1.1919x over previous
//
#include <hip/hip_runtime.h>

#define N_NODES 100000
#define IN_F 256
#define OUT_F 128
#define SCAN_ELEMS 1024
#define EDGE_ILP 8

typedef float f32x4 __attribute__((ext_vector_type(4)));
typedef __bf16 bf16x8 __attribute__((ext_vector_type(8)));

// RNE pack of two fp32 -> packed bf16x2
__device__ inline unsigned cvt2_bf16(float a, float b) {
  unsigned ua = __float_as_uint(a), ub = __float_as_uint(b);
  ua = (ua + 0x7fffu + ((ua >> 16) & 1u)) >> 16;
  ub = (ub + 0x7fffu + ((ub >> 16) & 1u)) >> 16;
  return ua | (ub << 16);
}
__device__ inline unsigned short cvt1_bf16(float a) {
  unsigned ua = __float_as_uint(a);
  return (unsigned short)((ua + 0x7fffu + ((ua >> 16) & 1u)) >> 16);
}

// -------- W pre-transpose into MFMA-B-frag order, fp32 -> bf16 --------
// chunk c = (nt*8 + kt)*64 + l holds 8 bf16: B[k = kt*32 + quad*8 + j][n = nt*16 + (l&15)]
__global__ __launch_bounds__(256) void transpose_w(const float* __restrict__ w,
                                                   uint4* __restrict__ wt) {
  int c = blockIdx.x * 256 + threadIdx.x;  // 4096 chunks
  int l = c & 63;
  int kt = (c >> 6) & 7;
  int nt = c >> 9;
  int n = nt * 16 + (l & 15);
  int kb = kt * 32 + ((l >> 4) & 3) * 8;
  unsigned d[4];
#pragma unroll
  for (int j = 0; j < 4; ++j) {
    float a = w[(size_t)(kb + 2 * j) * OUT_F + n];
    float b = w[(size_t)(kb + 2 * j + 1) * OUT_F + n];
    d[j] = cvt2_bf16(a, b);
  }
  wt[c] = make_uint4(d[0], d[1], d[2], d[3]);
}

// -------- support(bf16) = X @ W via bf16 MFMA, 128x128 tile --------
// LDS chunks are lane-contiguous (conflict-free); A-frag: m=lane&15, k=quad*8+j;
// C/D: col=lane&15, row=quad*4+reg  [m89-verified].
__global__ __launch_bounds__(256) void gemm_mfma(const float* __restrict__ x,
                                                 const uint4* __restrict__ wt,
                                                 unsigned short* __restrict__ sup) {
  __shared__ uint4 As[1024];  // 16 KB: 8 mt x 2 ktl x 64 lanes
  __shared__ uint4 Bs[1024];  // 16 KB: 8 nt x 2 ktl x 64 lanes
  const int t = threadIdx.x;
  const int lane = t & 63;
  const int wv = t >> 6;
  const int wm = wv >> 1, wn = wv & 1;  // 2x2 wave grid over 128x128
  const int row0 = blockIdx.x * 128;

  f32x4 acc[4][4];
#pragma unroll
  for (int mi = 0; mi < 4; ++mi)
#pragma unroll
    for (int ni = 0; ni < 4; ++ni) acc[mi][ni] = (f32x4){0.f, 0.f, 0.f, 0.f};

  for (int it = 0; it < 4; ++it) {  // K-tiles of 64
    const int k0 = it * 64;
#pragma unroll
    for (int i = 0; i < 4; ++i) {
      int ci = i * 256 + t;          // chunk 0..1023
      int g = ci >> 6, l = ci & 63;  // g = tile*2 + ktl
      int m = (g >> 1) * 16 + (l & 15);
      int k = k0 + (g & 1) * 32 + ((l >> 4) & 3) * 8;
      int row = row0 + m;
      if (row > N_NODES - 1) row = N_NODES - 1;
      const float* src = x + (size_t)row * IN_F + k;
      f32x4 v0 = *(const f32x4*)src;
      f32x4 v1 = *(const f32x4*)(src + 4);
      As[ci] = make_uint4(cvt2_bf16(v0.x, v0.y), cvt2_bf16(v0.z, v0.w),
                          cvt2_bf16(v1.x, v1.y), cvt2_bf16(v1.z, v1.w));
      Bs[ci] = wt[((g >> 1) * 8 + it * 2 + (g & 1)) * 64 + l];
    }
    __syncthreads();
#pragma unroll
    for (int ktl = 0; ktl < 2; ++ktl) {
      bf16x8 af[4], bfr[4];
#pragma unroll
      for (int mi = 0; mi < 4; ++mi)
        af[mi] = *(bf16x8*)&As[((wm * 4 + mi) * 2 + ktl) * 64 + lane];
#pragma unroll
      for (int ni = 0; ni < 4; ++ni)
        bfr[ni] = *(bf16x8*)&Bs[((wn * 4 + ni) * 2 + ktl) * 64 + lane];
#pragma unroll
      for (int mi = 0; mi < 4; ++mi)
#pragma unroll
        for (int ni = 0; ni < 4; ++ni)
          acc[mi][ni] = __builtin_amdgcn_mfma_f32_16x16x32_bf16(af[mi], bfr[ni],
                                                                acc[mi][ni], 0, 0, 0);
    }
    __syncthreads();
  }

  const int quad = lane >> 4, col = lane & 15;
#pragma unroll
  for (int mi = 0; mi < 4; ++mi) {
#pragma unroll
    for (int r = 0; r < 4; ++r) {
      int row = row0 + (wm * 4 + mi) * 16 + quad * 4 + r;
      if (row < N_NODES) {
#pragma unroll
        for (int ni = 0; ni < 4; ++ni)
          sup[(size_t)row * OUT_F + (wn * 4 + ni) * 16 + col] =
              cvt1_bf16(acc[mi][ni][r]);
      }
    }
  }
}

// -------- CSR build: histogram of dst, 8 edges/thread (atomic-latency ILP) ----
__global__ __launch_bounds__(256) void hist_dst(const int* __restrict__ ei,
                                                int* __restrict__ rowptr,
                                                int nedges, int nth) {
  int t = blockIdx.x * 256 + threadIdx.x;
  int d[EDGE_ILP], ok[EDGE_ILP];
#pragma unroll
  for (int j = 0; j < EDGE_ILP; ++j) {
    int e = t + j * nth;
    ok[j] = e < nedges;
    d[j] = ei[ok[j] ? e : 0];
  }
#pragma unroll
  for (int j = 0; j < EDGE_ILP; ++j)
    if (ok[j]) atomicAdd(&rowptr[d[j] + 1], 1);
}

// -------- in-place inclusive scan, 1024 elems / block --------
__global__ __launch_bounds__(256) void scan1(int* __restrict__ a,
                                             int* __restrict__ bsum, int n) {
  __shared__ int s[256];
  const int t = threadIdx.x;
  const int base = blockIdx.x * SCAN_ELEMS + t * 4;
  int v0 = (base + 0 < n) ? a[base + 0] : 0;
  int v1 = (base + 1 < n) ? a[base + 1] : 0;
  int v2 = (base + 2 < n) ? a[base + 2] : 0;
  int v3 = (base + 3 < n) ? a[base + 3] : 0;
  v1 += v0; v2 += v1; v3 += v2;
  s[t] = v3;
  __syncthreads();
  for (int off = 1; off < 256; off <<= 1) {
    int x = (t >= off) ? s[t - off] : 0;
    __syncthreads();
    s[t] += x;
    __syncthreads();
  }
  int excl = (t == 0) ? 0 : s[t - 1];
  if (base + 0 < n) a[base + 0] = v0 + excl;
  if (base + 1 < n) a[base + 1] = v1 + excl;
  if (base + 2 < n) a[base + 2] = v2 + excl;
  if (base + 3 < n) a[base + 3] = v3 + excl;
  if (t == 255 && bsum) bsum[blockIdx.x] = s[255];
}

__global__ __launch_bounds__(256) void scan3(int* __restrict__ a,
                                             const int* __restrict__ bsum, int n) {
  int b = blockIdx.x;
  if (b == 0) return;
  int add = bsum[b - 1];
  int i = b * SCAN_ELEMS + threadIdx.x * 4;
  if (i + 0 < n) a[i + 0] += add;
  if (i + 1 < n) a[i + 1] += add;
  if (i + 2 < n) a[i + 2] += add;
  if (i + 3 < n) a[i + 3] += add;
}

// -------- scatter edges into CSR slots, 8 edges/thread ILP --------
__global__ __launch_bounds__(256) void build_csr(const int* __restrict__ ei,
                                                 const float* __restrict__ ew,
                                                 int* __restrict__ cursor,
                                                 int2* __restrict__ edges,
                                                 int nedges, int nth) {
  int t = blockIdx.x * 256 + threadIdx.x;
  int d[EDGE_ILP], s[EDGE_ILP], ok[EDGE_ILP];
  float wvl[EDGE_ILP];
#pragma unroll
  for (int j = 0; j < EDGE_ILP; ++j) {
    int e = t + j * nth;
    ok[j] = e < nedges;
    int ee = ok[j] ? e : 0;
    d[j] = ei[ee];
    s[j] = ei[nedges + ee];
    wvl[j] = ew[ee];
  }
  int pos[EDGE_ILP];
#pragma unroll
  for (int j = 0; j < EDGE_ILP; ++j)
    pos[j] = ok[j] ? atomicAdd(&cursor[d[j]], 1) : 0;
#pragma unroll
  for (int j = 0; j < EDGE_ILP; ++j)
    if (ok[j]) edges[pos[j]] = make_int2(s[j], __float_as_int(wvl[j]));
}

// -------- aggregate: one wave per dst, bf16 support gather, no atomics --------
__global__ __launch_bounds__(256) void aggregate_bf16(const int* __restrict__ rowptr,
                                                      const int2* __restrict__ edges,
                                                      const unsigned short* __restrict__ sup,
                                                      float* __restrict__ out, int nnodes) {
  int wave = (int)((blockIdx.x * 256u + threadIdx.x) >> 6);
  int lane = threadIdx.x & 63;
  if (wave >= nnodes) return;
  int beg = rowptr[wave];
  int end = rowptr[wave + 1];
  float2 acc = make_float2(0.f, 0.f);
  int e = beg;
  for (; e + 4 <= end; e += 4) {
    int2 m0 = edges[e + 0];
    int2 m1 = edges[e + 1];
    int2 m2 = edges[e + 2];
    int2 m3 = edges[e + 3];
    unsigned u0 = *(const unsigned*)(sup + (size_t)m0.x * OUT_F + lane * 2);
    unsigned u1 = *(const unsigned*)(sup + (size_t)m1.x * OUT_F + lane * 2);
    unsigned u2 = *(const unsigned*)(sup + (size_t)m2.x * OUT_F + lane * 2);
    unsigned u3 = *(const unsigned*)(sup + (size_t)m3.x * OUT_F + lane * 2);
    float w0 = __int_as_float(m0.y), w1 = __int_as_float(m1.y);
    float w2 = __int_as_float(m2.y), w3 = __int_as_float(m3.y);
    acc.x = fmaf(__uint_as_float(u0 << 16), w0, acc.x);
    acc.y = fmaf(__uint_as_float(u0 & 0xffff0000u), w0, acc.y);
    acc.x = fmaf(__uint_as_float(u1 << 16), w1, acc.x);
    acc.y = fmaf(__uint_as_float(u1 & 0xffff0000u), w1, acc.y);
    acc.x = fmaf(__uint_as_float(u2 << 16), w2, acc.x);
    acc.y = fmaf(__uint_as_float(u2 & 0xffff0000u), w2, acc.y);
    acc.x = fmaf(__uint_as_float(u3 << 16), w3, acc.x);
    acc.y = fmaf(__uint_as_float(u3 & 0xffff0000u), w3, acc.y);
  }
  for (; e < end; ++e) {
    int2 m = edges[e];
    unsigned u = *(const unsigned*)(sup + (size_t)m.x * OUT_F + lane * 2);
    float w = __int_as_float(m.y);
    acc.x = fmaf(__uint_as_float(u << 16), w, acc.x);
    acc.y = fmaf(__uint_as_float(u & 0xffff0000u), w, acc.y);
  }
  *(float2*)(out + (size_t)wave * OUT_F + lane * 2) = acc;
}

// -------- fallback: atomic scatter (only if ws too small) --------
__global__ __launch_bounds__(256) void scatter_edges(const int* __restrict__ ei,
                                                     const float* __restrict__ ew,
                                                     const unsigned short* __restrict__ sup,
                                                     float* __restrict__ out, int nedges) {
  int gwave = (int)((blockIdx.x * 256u + threadIdx.x) >> 6);
  int lane = threadIdx.x & 63;
  if (gwave >= nedges) return;
  int dst = ei[gwave];
  int src = ei[nedges + gwave];
  float wgt = ew[gwave];
  unsigned u = *(const unsigned*)(sup + (size_t)src * OUT_F + lane * 2);
  float* op = out + (size_t)dst * OUT_F + lane * 2;
  atomicAdd(op, __uint_as_float(u << 16) * wgt);
  atomicAdd(op + 1, __uint_as_float(u & 0xffff0000u) * wgt);
}

extern "C" void kernel_launch(void* const* d_in, const int* in_sizes, int n_in,
                              void* d_out, int out_size, void* d_ws, size_t ws_size,
                              hipStream_t stream) {
  const float* x = (const float*)d_in[0];
  const int* ei = (const int*)d_in[1];      // [2, E] int32 flat: row0=dst, row1=src
  const float* ew = (const float*)d_in[2];  // [E]
  const float* w = (const float*)d_in[3];   // [256,128]
  float* out = (float*)d_out;
  const int nedges = in_sizes[2];

  // workspace layout (bytes)
  const size_t off_support = 0;
  const size_t sz_support = (size_t)N_NODES * OUT_F * 2;  // 25,600,000 (bf16)
  const size_t off_rowptr = off_support + sz_support;     // 25,600,000 (8-aligned)
  const size_t sz_rowptr = (size_t)(N_NODES + 1) * 4;     // 400,004
  const size_t off_cursor = off_rowptr + 400008;          // 26,000,008
  const size_t off_bsum = off_cursor + 400000;            // 26,400,008
  const size_t off_wt = off_bsum + 408;                   // 26,400,416 (16-aligned)
  const size_t sz_wt = 4096 * 16;                         // 65,536
  const size_t off_edges = off_wt + sz_wt;                // 26,465,952 (8-aligned)
  const size_t total_ws = off_edges + (size_t)nedges * 8;

  unsigned short* support = (unsigned short*)((char*)d_ws + off_support);
  int* rowptr = (int*)((char*)d_ws + off_rowptr);
  int* cursor = (int*)((char*)d_ws + off_cursor);
  int* bsum = (int*)((char*)d_ws + off_bsum);
  uint4* wt = (uint4*)((char*)d_ws + off_wt);
  int2* edges = (int2*)((char*)d_ws + off_edges);

  transpose_w<<<16, 256, 0, stream>>>(w, wt);
  const int gblocks = (N_NODES + 127) / 128;  // 782
  gemm_mfma<<<gblocks, 256, 0, stream>>>(x, wt, support);

  if (ws_size < total_ws) {
    hipMemsetAsync(d_out, 0, (size_t)out_size * sizeof(float), stream);
    int sblocks = (nedges + 3) / 4;
    scatter_edges<<<sblocks, 256, 0, stream>>>(ei, ew, support, out, nedges);
    return;
  }

  const int n1 = N_NODES + 1;
  const int nb = (n1 + SCAN_ELEMS - 1) / SCAN_ELEMS;    // 98
  const int eblocks = (nedges / EDGE_ILP + 255) / 256;  // 782
  const int nth = eblocks * 256;

  hipMemsetAsync(rowptr, 0, sz_rowptr, stream);
  hist_dst<<<eblocks, 256, 0, stream>>>(ei, rowptr, nedges, nth);
  scan1<<<nb, 256, 0, stream>>>(rowptr, bsum, n1);
  scan1<<<1, 256, 0, stream>>>(bsum, (int*)nullptr, nb);
  scan3<<<nb, 256, 0, stream>>>(rowptr, bsum, n1);
  hipMemcpyAsync(cursor, rowptr, (size_t)N_NODES * 4, hipMemcpyDeviceToDevice, stream);
  build_csr<<<eblocks, 256, 0, stream>>>(ei, ew, cursor, edges, nedges, nth);

  const int ablocks = (N_NODES + 3) / 4;
  aggregate_bf16<<<ablocks, 256, 0, stream>>>(rowptr, edges, support, out, N_NODES);
}

// Round 6
// 328.402 us; speedup vs baseline: 4.6775x; 1.3244x over previous
//
#include <hip/hip_runtime.h>

#define N_NODES 100000
#define IN_F 256
#define OUT_F 128
#define SCAN_ELEMS 1024
#define EDGE_ILP 8

typedef float f32x4 __attribute__((ext_vector_type(4)));
typedef __bf16 bf16x8 __attribute__((ext_vector_type(8)));

// RNE pack of two fp32 -> packed bf16x2
__device__ inline unsigned cvt2_bf16(float a, float b) {
  unsigned ua = __float_as_uint(a), ub = __float_as_uint(b);
  ua = (ua + 0x7fffu + ((ua >> 16) & 1u)) >> 16;
  ub = (ub + 0x7fffu + ((ub >> 16) & 1u)) >> 16;
  return ua | (ub << 16);
}
__device__ inline unsigned short cvt1_bf16(float a) {
  unsigned ua = __float_as_uint(a);
  return (unsigned short)((ua + 0x7fffu + ((ua >> 16) & 1u)) >> 16);
}

// -------- W pre-transpose into MFMA-B-frag order, fp32 -> bf16 --------
// chunk c = (nt*8 + kt)*64 + l holds 8 bf16: B[k = kt*32 + quad*8 + j][n = nt*16 + (l&15)]
__global__ __launch_bounds__(256) void transpose_w(const float* __restrict__ w,
                                                   uint4* __restrict__ wt) {
  int c = blockIdx.x * 256 + threadIdx.x;  // 4096 chunks
  int l = c & 63;
  int kt = (c >> 6) & 7;
  int nt = c >> 9;
  int n = nt * 16 + (l & 15);
  int kb = kt * 32 + ((l >> 4) & 3) * 8;
  unsigned d[4];
#pragma unroll
  for (int j = 0; j < 4; ++j) {
    float a = w[(size_t)(kb + 2 * j) * OUT_F + n];
    float b = w[(size_t)(kb + 2 * j + 1) * OUT_F + n];
    d[j] = cvt2_bf16(a, b);
  }
  wt[c] = make_uint4(d[0], d[1], d[2], d[3]);
}

// -------- fused: even blocks = MFMA GEMM tile, odd blocks = dst histogram ----
// hist role is scatter/latency-bound with idle ALU; gemm role is MFMA-bound.
// Co-residency on each CU overlaps them.
__global__ __launch_bounds__(256) void gemm_hist(const float* __restrict__ x,
                                                 const uint4* __restrict__ wt,
                                                 unsigned short* __restrict__ sup,
                                                 const int* __restrict__ ei,
                                                 int* __restrict__ rowptr,
                                                 int* __restrict__ rank,
                                                 int nedges, int nth) {
  __shared__ uint4 As[1024];  // 16 KB
  __shared__ uint4 Bs[1024];  // 16 KB
  const int gid = blockIdx.x;
  const int sub = gid >> 1;

  if (gid & 1) {
    // ---- hist role: rank[e] = old count of dst, counts into rowptr[d+1] ----
    int t = sub * 256 + threadIdx.x;
    int d[EDGE_ILP], ok[EDGE_ILP];
#pragma unroll
    for (int j = 0; j < EDGE_ILP; ++j) {
      int e = t + j * nth;
      ok[j] = e < nedges;
      d[j] = ei[ok[j] ? e : 0];
    }
    int rk[EDGE_ILP];
#pragma unroll
    for (int j = 0; j < EDGE_ILP; ++j)
      rk[j] = ok[j] ? atomicAdd(&rowptr[d[j] + 1], 1) : 0;
#pragma unroll
    for (int j = 0; j < EDGE_ILP; ++j) {
      int e = t + j * nth;
      if (ok[j]) rank[e] = rk[j];  // coalesced store
    }
    return;
  }

  // ---- gemm role: support(bf16) = X @ W, 128x128 tile (round-5 body) ----
  const int t = threadIdx.x;
  const int lane = t & 63;
  const int wv = t >> 6;
  const int wm = wv >> 1, wn = wv & 1;
  const int row0 = sub * 128;

  f32x4 acc[4][4];
#pragma unroll
  for (int mi = 0; mi < 4; ++mi)
#pragma unroll
    for (int ni = 0; ni < 4; ++ni) acc[mi][ni] = (f32x4){0.f, 0.f, 0.f, 0.f};

  for (int it = 0; it < 4; ++it) {
    const int k0 = it * 64;
#pragma unroll
    for (int i = 0; i < 4; ++i) {
      int ci = i * 256 + t;
      int g = ci >> 6, l = ci & 63;
      int m = (g >> 1) * 16 + (l & 15);
      int k = k0 + (g & 1) * 32 + ((l >> 4) & 3) * 8;
      int row = row0 + m;
      if (row > N_NODES - 1) row = N_NODES - 1;
      const float* src = x + (size_t)row * IN_F + k;
      f32x4 v0 = *(const f32x4*)src;
      f32x4 v1 = *(const f32x4*)(src + 4);
      As[ci] = make_uint4(cvt2_bf16(v0.x, v0.y), cvt2_bf16(v0.z, v0.w),
                          cvt2_bf16(v1.x, v1.y), cvt2_bf16(v1.z, v1.w));
      Bs[ci] = wt[((g >> 1) * 8 + it * 2 + (g & 1)) * 64 + l];
    }
    __syncthreads();
#pragma unroll
    for (int ktl = 0; ktl < 2; ++ktl) {
      bf16x8 af[4], bfr[4];
#pragma unroll
      for (int mi = 0; mi < 4; ++mi)
        af[mi] = *(bf16x8*)&As[((wm * 4 + mi) * 2 + ktl) * 64 + lane];
#pragma unroll
      for (int ni = 0; ni < 4; ++ni)
        bfr[ni] = *(bf16x8*)&Bs[((wn * 4 + ni) * 2 + ktl) * 64 + lane];
#pragma unroll
      for (int mi = 0; mi < 4; ++mi)
#pragma unroll
        for (int ni = 0; ni < 4; ++ni)
          acc[mi][ni] = __builtin_amdgcn_mfma_f32_16x16x32_bf16(af[mi], bfr[ni],
                                                                acc[mi][ni], 0, 0, 0);
    }
    __syncthreads();
  }

  const int quad = lane >> 4, col = lane & 15;
#pragma unroll
  for (int mi = 0; mi < 4; ++mi) {
#pragma unroll
    for (int r = 0; r < 4; ++r) {
      int row = row0 + (wm * 4 + mi) * 16 + quad * 4 + r;
      if (row < N_NODES) {
#pragma unroll
        for (int ni = 0; ni < 4; ++ni)
          sup[(size_t)row * OUT_F + (wn * 4 + ni) * 16 + col] =
              cvt1_bf16(acc[mi][ni][r]);
      }
    }
  }
}

// -------- standalone gemm (fallback path only) --------
__global__ __launch_bounds__(256) void gemm_mfma(const float* __restrict__ x,
                                                 const uint4* __restrict__ wt,
                                                 unsigned short* __restrict__ sup) {
  __shared__ uint4 As[1024];
  __shared__ uint4 Bs[1024];
  const int t = threadIdx.x;
  const int lane = t & 63;
  const int wv = t >> 6;
  const int wm = wv >> 1, wn = wv & 1;
  const int row0 = blockIdx.x * 128;

  f32x4 acc[4][4];
#pragma unroll
  for (int mi = 0; mi < 4; ++mi)
#pragma unroll
    for (int ni = 0; ni < 4; ++ni) acc[mi][ni] = (f32x4){0.f, 0.f, 0.f, 0.f};

  for (int it = 0; it < 4; ++it) {
    const int k0 = it * 64;
#pragma unroll
    for (int i = 0; i < 4; ++i) {
      int ci = i * 256 + t;
      int g = ci >> 6, l = ci & 63;
      int m = (g >> 1) * 16 + (l & 15);
      int k = k0 + (g & 1) * 32 + ((l >> 4) & 3) * 8;
      int row = row0 + m;
      if (row > N_NODES - 1) row = N_NODES - 1;
      const float* src = x + (size_t)row * IN_F + k;
      f32x4 v0 = *(const f32x4*)src;
      f32x4 v1 = *(const f32x4*)(src + 4);
      As[ci] = make_uint4(cvt2_bf16(v0.x, v0.y), cvt2_bf16(v0.z, v0.w),
                          cvt2_bf16(v1.x, v1.y), cvt2_bf16(v1.z, v1.w));
      Bs[ci] = wt[((g >> 1) * 8 + it * 2 + (g & 1)) * 64 + l];
    }
    __syncthreads();
#pragma unroll
    for (int ktl = 0; ktl < 2; ++ktl) {
      bf16x8 af[4], bfr[4];
#pragma unroll
      for (int mi = 0; mi < 4; ++mi)
        af[mi] = *(bf16x8*)&As[((wm * 4 + mi) * 2 + ktl) * 64 + lane];
#pragma unroll
      for (int ni = 0; ni < 4; ++ni)
        bfr[ni] = *(bf16x8*)&Bs[((wn * 4 + ni) * 2 + ktl) * 64 + lane];
#pragma unroll
      for (int mi = 0; mi < 4; ++mi)
#pragma unroll
        for (int ni = 0; ni < 4; ++ni)
          acc[mi][ni] = __builtin_amdgcn_mfma_f32_16x16x32_bf16(af[mi], bfr[ni],
                                                                acc[mi][ni], 0, 0, 0);
    }
    __syncthreads();
  }

  const int quad = lane >> 4, col = lane & 15;
#pragma unroll
  for (int mi = 0; mi < 4; ++mi) {
#pragma unroll
    for (int r = 0; r < 4; ++r) {
      int row = row0 + (wm * 4 + mi) * 16 + quad * 4 + r;
      if (row < N_NODES) {
#pragma unroll
        for (int ni = 0; ni < 4; ++ni)
          sup[(size_t)row * OUT_F + (wn * 4 + ni) * 16 + col] =
              cvt1_bf16(acc[mi][ni][r]);
      }
    }
  }
}

// -------- in-place inclusive scan, 1024 elems / block --------
__global__ __launch_bounds__(256) void scan1(int* __restrict__ a,
                                             int* __restrict__ bsum, int n) {
  __shared__ int s[256];
  const int t = threadIdx.x;
  const int base = blockIdx.x * SCAN_ELEMS + t * 4;
  int v0 = (base + 0 < n) ? a[base + 0] : 0;
  int v1 = (base + 1 < n) ? a[base + 1] : 0;
  int v2 = (base + 2 < n) ? a[base + 2] : 0;
  int v3 = (base + 3 < n) ? a[base + 3] : 0;
  v1 += v0; v2 += v1; v3 += v2;
  s[t] = v3;
  __syncthreads();
  for (int off = 1; off < 256; off <<= 1) {
    int x = (t >= off) ? s[t - off] : 0;
    __syncthreads();
    s[t] += x;
    __syncthreads();
  }
  int excl = (t == 0) ? 0 : s[t - 1];
  if (base + 0 < n) a[base + 0] = v0 + excl;
  if (base + 1 < n) a[base + 1] = v1 + excl;
  if (base + 2 < n) a[base + 2] = v2 + excl;
  if (base + 3 < n) a[base + 3] = v3 + excl;
  if (t == 255 && bsum) bsum[blockIdx.x] = s[255];
}

__global__ __launch_bounds__(256) void scan3(int* __restrict__ a,
                                             const int* __restrict__ bsum, int n) {
  int b = blockIdx.x;
  if (b == 0) return;
  int add = bsum[b - 1];
  int i = b * SCAN_ELEMS + threadIdx.x * 4;
  if (i + 0 < n) a[i + 0] += add;
  if (i + 1 < n) a[i + 1] += add;
  if (i + 2 < n) a[i + 2] += add;
  if (i + 3 < n) a[i + 3] += add;
}

// -------- scatter edges into CSR slots — NO atomics (rank precomputed) ----
__global__ __launch_bounds__(256) void build_scatter(const int* __restrict__ ei,
                                                     const float* __restrict__ ew,
                                                     const int* __restrict__ rowptr,
                                                     const int* __restrict__ rank,
                                                     int2* __restrict__ edges,
                                                     int nedges, int nth) {
  int t = blockIdx.x * 256 + threadIdx.x;
  int d[EDGE_ILP], s[EDGE_ILP], ok[EDGE_ILP], rk[EDGE_ILP];
  float wvl[EDGE_ILP];
#pragma unroll
  for (int j = 0; j < EDGE_ILP; ++j) {
    int e = t + j * nth;
    ok[j] = e < nedges;
    int ee = ok[j] ? e : 0;
    d[j] = ei[ee];
    s[j] = ei[nedges + ee];
    wvl[j] = ew[ee];
    rk[j] = rank[ee];
  }
#pragma unroll
  for (int j = 0; j < EDGE_ILP; ++j) {
    if (ok[j]) {
      int pos = rowptr[d[j]] + rk[j];
      edges[pos] = make_int2(s[j], __float_as_int(wvl[j]));
    }
  }
}

// -------- aggregate: one wave per dst, bf16 support gather, no atomics --------
__global__ __launch_bounds__(256) void aggregate_bf16(const int* __restrict__ rowptr,
                                                      const int2* __restrict__ edges,
                                                      const unsigned short* __restrict__ sup,
                                                      float* __restrict__ out, int nnodes) {
  int wave = (int)((blockIdx.x * 256u + threadIdx.x) >> 6);
  int lane = threadIdx.x & 63;
  if (wave >= nnodes) return;
  int beg = rowptr[wave];
  int end = rowptr[wave + 1];
  float2 acc = make_float2(0.f, 0.f);
  int e = beg;
  for (; e + 4 <= end; e += 4) {
    int2 m0 = edges[e + 0];
    int2 m1 = edges[e + 1];
    int2 m2 = edges[e + 2];
    int2 m3 = edges[e + 3];
    unsigned u0 = *(const unsigned*)(sup + (size_t)m0.x * OUT_F + lane * 2);
    unsigned u1 = *(const unsigned*)(sup + (size_t)m1.x * OUT_F + lane * 2);
    unsigned u2 = *(const unsigned*)(sup + (size_t)m2.x * OUT_F + lane * 2);
    unsigned u3 = *(const unsigned*)(sup + (size_t)m3.x * OUT_F + lane * 2);
    float w0 = __int_as_float(m0.y), w1 = __int_as_float(m1.y);
    float w2 = __int_as_float(m2.y), w3 = __int_as_float(m3.y);
    acc.x = fmaf(__uint_as_float(u0 << 16), w0, acc.x);
    acc.y = fmaf(__uint_as_float(u0 & 0xffff0000u), w0, acc.y);
    acc.x = fmaf(__uint_as_float(u1 << 16), w1, acc.x);
    acc.y = fmaf(__uint_as_float(u1 & 0xffff0000u), w1, acc.y);
    acc.x = fmaf(__uint_as_float(u2 << 16), w2, acc.x);
    acc.y = fmaf(__uint_as_float(u2 & 0xffff0000u), w2, acc.y);
    acc.x = fmaf(__uint_as_float(u3 << 16), w3, acc.x);
    acc.y = fmaf(__uint_as_float(u3 & 0xffff0000u), w3, acc.y);
  }
  for (; e < end; ++e) {
    int2 m = edges[e];
    unsigned u = *(const unsigned*)(sup + (size_t)m.x * OUT_F + lane * 2);
    float w = __int_as_float(m.y);
    acc.x = fmaf(__uint_as_float(u << 16), w, acc.x);
    acc.y = fmaf(__uint_as_float(u & 0xffff0000u), w, acc.y);
  }
  *(float2*)(out + (size_t)wave * OUT_F + lane * 2) = acc;
}

// -------- fallback: atomic scatter (only if ws too small) --------
__global__ __launch_bounds__(256) void scatter_edges(const int* __restrict__ ei,
                                                     const float* __restrict__ ew,
                                                     const unsigned short* __restrict__ sup,
                                                     float* __restrict__ out, int nedges) {
  int gwave = (int)((blockIdx.x * 256u + threadIdx.x) >> 6);
  int lane = threadIdx.x & 63;
  if (gwave >= nedges) return;
  int dst = ei[gwave];
  int src = ei[nedges + gwave];
  float wgt = ew[gwave];
  unsigned u = *(const unsigned*)(sup + (size_t)src * OUT_F + lane * 2);
  float* op = out + (size_t)dst * OUT_F + lane * 2;
  atomicAdd(op, __uint_as_float(u << 16) * wgt);
  atomicAdd(op + 1, __uint_as_float(u & 0xffff0000u) * wgt);
}

extern "C" void kernel_launch(void* const* d_in, const int* in_sizes, int n_in,
                              void* d_out, int out_size, void* d_ws, size_t ws_size,
                              hipStream_t stream) {
  const float* x = (const float*)d_in[0];
  const int* ei = (const int*)d_in[1];      // [2, E] int32 flat: row0=dst, row1=src
  const float* ew = (const float*)d_in[2];  // [E]
  const float* w = (const float*)d_in[3];   // [256,128]
  float* out = (float*)d_out;
  const int nedges = in_sizes[2];

  // workspace layout (bytes)
  const size_t off_support = 0;
  const size_t sz_support = (size_t)N_NODES * OUT_F * 2;  // 25,600,000 (bf16)
  const size_t off_rowptr = off_support + sz_support;     // 25,600,000
  const size_t sz_rowptr = (size_t)(N_NODES + 1) * 4;     // 400,004 -> pad 400,008
  const size_t off_bsum = off_rowptr + 400008;            // 26,000,008
  const size_t off_wt = off_bsum + 408;                   // 26,000,416 (16-aligned)
  const size_t sz_wt = 4096 * 16;                         // 65,536
  const size_t off_rank = off_wt + sz_wt;                 // 26,065,952
  const size_t off_edges = off_rank + (size_t)nedges * 4; // 32,465,952
  const size_t total_ws = off_edges + (size_t)nedges * 8; // 45,265,952

  unsigned short* support = (unsigned short*)((char*)d_ws + off_support);
  int* rowptr = (int*)((char*)d_ws + off_rowptr);
  int* bsum = (int*)((char*)d_ws + off_bsum);
  uint4* wt = (uint4*)((char*)d_ws + off_wt);
  int* rank = (int*)((char*)d_ws + off_rank);
  int2* edges = (int2*)((char*)d_ws + off_edges);

  transpose_w<<<16, 256, 0, stream>>>(w, wt);

  if (ws_size < total_ws) {
    const int gblocks = (N_NODES + 127) / 128;
    gemm_mfma<<<gblocks, 256, 0, stream>>>(x, wt, support);
    hipMemsetAsync(d_out, 0, (size_t)out_size * sizeof(float), stream);
    int sblocks = (nedges + 3) / 4;
    scatter_edges<<<sblocks, 256, 0, stream>>>(ei, ew, support, out, nedges);
    return;
  }

  const int n1 = N_NODES + 1;
  const int nb = (n1 + SCAN_ELEMS - 1) / SCAN_ELEMS;    // 98
  const int eblocks = (nedges / EDGE_ILP + 255) / 256;  // 782
  const int nth = eblocks * 256;                        // 200192
  const int gblocks = (N_NODES + 127) / 128;            // 782

  hipMemsetAsync(rowptr, 0, sz_rowptr, stream);
  // fused: even blocks gemm (782), odd blocks hist (782)
  gemm_hist<<<gblocks + eblocks, 256, 0, stream>>>(x, wt, support, ei, rowptr,
                                                   rank, nedges, nth);
  scan1<<<nb, 256, 0, stream>>>(rowptr, bsum, n1);
  scan1<<<1, 256, 0, stream>>>(bsum, (int*)nullptr, nb);
  scan3<<<nb, 256, 0, stream>>>(rowptr, bsum, n1);
  build_scatter<<<eblocks, 256, 0, stream>>>(ei, ew, rowptr, rank, edges, nedges, nth);

  const int ablocks = (N_NODES + 3) / 4;
  aggregate_bf16<<<ablocks, 256, 0, stream>>>(rowptr, edges, support, out, N_NODES);
}